// Round 8
// baseline (429.113 us; speedup 1.0000x reference)
//
#include <hip/hip_runtime.h>

#define BSZ 16
#define SSZ 8192
#define F4  64
#define EPSV 1e-5f
#define SEGCAP 256     // nseg ~131 expected; guards prevent OOB beyond this
#define CHCAP  384     // max chunks = SSZ/CH (128) + SEGCAP partial chunks
#define CH 64
#define NBLK 1024      // == guaranteed co-resident blocks at 4/CU x 256 CU
#define NTHR 256

typedef float f32x4 __attribute__((ext_vector_type(4)));

// --- Kernel 1: ind[s] = any_b(cp[b,s]), ind[0]=0 -------------------------
__global__ void cp_reduce_kernel(const int* __restrict__ cp, int* __restrict__ ind) {
    int s = blockIdx.x * blockDim.x + threadIdx.x;
    if (s >= SSZ) return;
    int a = 0;
#pragma unroll
    for (int b = 0; b < BSZ; ++b) a |= cp[b * SSZ + s];
    ind[s] = (s == 0) ? 0 : (a != 0 ? 1 : 0);
}

// --- Kernel 2: scan -> per-chunk metadata; zero spin counters ------------
__global__ __launch_bounds__(1024) void scan_kernel(const int* __restrict__ ind,
                                                    int* __restrict__ ch_s0,
                                                    int* __restrict__ ch_s1,
                                                    int* __restrict__ ch_c0,
                                                    int* __restrict__ ch_n,
                                                    float* __restrict__ ch_rc,
                                                    int* __restrict__ ctr,
                                                    int* __restrict__ meta) {
    __shared__ int ldsi[1024];
    __shared__ int sstart[SEGCAP];
    __shared__ int snseg;
    const int t = threadIdx.x;
    // zero counters for this launch (replay-safe: runs before segnorm uses them)
    for (int i = t; i < CHCAP * BSZ; i += 1024) ctr[i] = 0;

    int vals[8];
    int tot = 0;
#pragma unroll
    for (int i = 0; i < 8; ++i) { int v = ind[t * 8 + i]; vals[i] = v; tot += v; }
    ldsi[t] = tot;
    __syncthreads();
    for (int off = 1; off < 1024; off <<= 1) {
        int a = ldsi[t];
        int b = (t >= off) ? ldsi[t - off] : 0;
        __syncthreads();
        ldsi[t] = a + b;
        __syncthreads();
    }
    int run = ldsi[t] - tot;  // exclusive prefix
#pragma unroll
    for (int i = 0; i < 8; ++i) {
        run += vals[i];
        if (vals[i] && run < SEGCAP) sstart[run] = t * 8 + i;
    }
    if (t == 0) sstart[0] = 0;
    if (t == 1023) { int n = ldsi[1023] + 1; snseg = n < SEGCAP ? n : SEGCAP; }
    __syncthreads();

    const int nseg = snseg;
    int st = 0, en = 0, nch = 0;
    if (t < nseg) {
        st = sstart[t];
        en = (t + 1 < nseg) ? sstart[t + 1] : SSZ;
        nch = (en - st + CH - 1) / CH;
    }
    ldsi[t] = nch;
    __syncthreads();
    for (int off = 1; off < 1024; off <<= 1) {
        int a = ldsi[t];
        int b = (t >= off) ? ldsi[t - off] : 0;
        __syncthreads();
        ldsi[t] = a + b;
        __syncthreads();
    }
    const int cbase = ldsi[t] - nch;  // exclusive prefix
    if (t < nseg) {
        const float rc = 1.0f / (float)(en - st);
        for (int j = 0; j < nch; ++j) {
            const int c = cbase + j;
            ch_s0[c] = st + j * CH;
            ch_s1[c] = min(en, st + (j + 1) * CH);
            ch_c0[c] = cbase;
            ch_n[c]  = nch;
            ch_rc[c] = rc;
        }
    }
    if (t == 1023) {
        meta[0] = ldsi[1023] * BSZ;  // nitems
        meta[1] = ldsi[1023];        // nchunks
    }
}

// --- Kernel 3: single-pass segnorm with cross-block segment handshake ----
// item = b * nchunks + c  (b-major: a (seg,b) group's items are contiguous,
// span = nchunks(seg) <= 128 <= NBLK -> wait graph acyclic; all NBLK blocks
// co-resident via __launch_bounds__(256,4) -> deadlock-free).
__global__ __launch_bounds__(NTHR, 4) void segnorm_kernel(
    const f32x4* __restrict__ x4,
    const f32x4* __restrict__ w4p, const f32x4* __restrict__ b4p,
    const int* __restrict__ ch_s0, const int* __restrict__ ch_s1,
    const int* __restrict__ ch_c0, const int* __restrict__ ch_n,
    const float* __restrict__ ch_rc, const int* __restrict__ meta,
    f32x4* __restrict__ psum, f32x4* __restrict__ pssq,
    int* __restrict__ ctr, f32x4* __restrict__ out4)
{
    __shared__ f32x4 lsum[4][64];
    __shared__ f32x4 lssq[4][64];
    const int nitems = meta[0];
    const int nchunks = meta[1];
    const int lane = threadIdx.x & 63;
    const int wave = threadIdx.x >> 6;
    const f32x4 w = w4p[lane];
    const f32x4 bb = b4p[lane];

    for (int item = blockIdx.x; item < nitems; item += NBLK) {
        const int b = item / nchunks;
        const int c = item - b * nchunks;
        const int s0 = ch_s0[c], s1 = ch_s1[c];
        const int c0 = ch_c0[c], n = ch_n[c];
        const float rc = ch_rc[c];
        const f32x4* px = x4 + (size_t)b * SSZ * F4 + lane;

        // pass 1: read chunk rows into REGISTERS, accumulate partial moments
        f32x4 v[16];
        f32x4 sum = {0.f, 0.f, 0.f, 0.f};
        f32x4 ssq = {0.f, 0.f, 0.f, 0.f};
        const int r0 = s0 + wave;
#pragma unroll
        for (int r = 0; r < 16; ++r) {
            const int s = r0 + 4 * r;           // wave-uniform guard
            if (s < s1) { v[r] = px[(size_t)s * F4]; sum += v[r]; ssq += v[r] * v[r]; }
        }

        f32x4 S, Q;
        lsum[wave][lane] = sum;
        lssq[wave][lane] = ssq;
        __syncthreads();
        if (n == 1) {
            // fast path: whole segment in this block -> stats from LDS only
            S = lsum[0][lane] + lsum[1][lane] + lsum[2][lane] + lsum[3][lane];
            Q = lssq[0][lane] + lssq[1][lane] + lssq[2][lane] + lssq[3][lane];
            __syncthreads();
        } else {
            // publish this chunk's partial
            if (wave == 0) {
                f32x4 o = lsum[0][lane] + lsum[1][lane] + lsum[2][lane] + lsum[3][lane];
                psum[((size_t)c * BSZ + b) * F4 + lane] = o;
            } else if (wave == 1) {
                f32x4 o = lssq[0][lane] + lssq[1][lane] + lssq[2][lane] + lssq[3][lane];
                pssq[((size_t)c * BSZ + b) * F4 + lane] = o;
            }
            __threadfence();     // device-scope: partials visible before count
            __syncthreads();
            const int key = b * CHCAP + c0;
            if (threadIdx.x == 0) {
                __hip_atomic_fetch_add(&ctr[key], 1, __ATOMIC_RELEASE,
                                       __HIP_MEMORY_SCOPE_AGENT);
                while (__hip_atomic_load(&ctr[key], __ATOMIC_ACQUIRE,
                                         __HIP_MEMORY_SCOPE_AGENT) < n) {
                    __builtin_amdgcn_s_sleep(2);
                }
            }
            __syncthreads();
            // all chunk partials of (seg,b) now visible: reduce them
            S = {0.f, 0.f, 0.f, 0.f};
            Q = {0.f, 0.f, 0.f, 0.f};
            for (int cc = c0; cc < c0 + n; ++cc) {
                S += psum[((size_t)cc * BSZ + b) * F4 + lane];
                Q += pssq[((size_t)cc * BSZ + b) * F4 + lane];
            }
        }

        const f32x4 m = S * rc;
        f32x4 var = Q * rc - m * m;
        f32x4 rs;
        rs.x = 1.0f / sqrtf(fmaxf(var.x, 0.f) + EPSV);
        rs.y = 1.0f / sqrtf(fmaxf(var.y, 0.f) + EPSV);
        rs.z = 1.0f / sqrtf(fmaxf(var.z, 0.f) + EPSV);
        rs.w = 1.0f / sqrtf(fmaxf(var.w, 0.f) + EPSV);

        // pass 2: normalize straight from registers -> no second x read
        f32x4* po = out4 + (size_t)b * SSZ * F4 + lane;
#pragma unroll
        for (int r = 0; r < 16; ++r) {
            const int s = r0 + 4 * r;
            if (s < s1) {
                f32x4 o = (v[r] - m) * rs * w + bb;
                __builtin_nontemporal_store(o, &po[(size_t)s * F4]);
            }
        }
    }
}

extern "C" void kernel_launch(void* const* d_in, const int* in_sizes, int n_in,
                              void* d_out, int out_size, void* d_ws, size_t ws_size,
                              hipStream_t stream) {
    const f32x4* x = (const f32x4*)d_in[0];
    const f32x4* w = (const f32x4*)d_in[1];
    const f32x4* bias = (const f32x4*)d_in[2];
    const int* cp = (const int*)d_in[3];

    char* ws = (char*)d_ws;
    int*   meta  = (int*)ws;                 // [16]
    int*   ch_s0 = (int*)(ws + 2048);        // [CHCAP]
    int*   ch_s1 = (int*)(ws + 4096);        // [CHCAP]
    int*   ch_c0 = (int*)(ws + 6144);        // [CHCAP]
    int*   ch_n  = (int*)(ws + 8192);        // [CHCAP]
    float* ch_rc = (float*)(ws + 10240);     // [CHCAP]
    int*   ctr   = (int*)(ws + 32768);       // [CHCAP*BSZ] = 24 KB
    int*   ind   = (int*)(ws + 65536);       // [SSZ]
    f32x4* psum  = (f32x4*)(ws + 131072);    // CHCAP*BSZ*F4 f32x4 = 6.29 MB
    f32x4* pssq  = psum + (size_t)CHCAP * BSZ * F4;

    cp_reduce_kernel<<<(SSZ + 255) / 256, 256, 0, stream>>>(cp, ind);
    scan_kernel<<<1, 1024, 0, stream>>>(ind, ch_s0, ch_s1, ch_c0, ch_n, ch_rc,
                                        ctr, meta);
    segnorm_kernel<<<NBLK, NTHR, 0, stream>>>(x, w, bias, ch_s0, ch_s1, ch_c0,
                                              ch_n, ch_rc, meta, psum, pssq,
                                              ctr, (f32x4*)d_out);
}

// Round 9
// 331.566 us; speedup vs baseline: 1.2942x; 1.2942x over previous
//
#include <hip/hip_runtime.h>

#define BSZ 16
#define SSZ 8192
#define F4  64
#define EPSV 1e-5f
#define SEGCAP 256     // nseg ~131 expected (sigma ~11) -> huge margin
#define CHCAP  384     // max chunks = SSZ/CH (128) + SEGCAP
#define CH 64
#define NBLK_S 3072
#define NBLK_N 2048

typedef float f32x4 __attribute__((ext_vector_type(4)));

// --- Kernel 1: ind[s] = any_b(cp[b,s]), ind[0]=0 -------------------------
__global__ void cp_reduce_kernel(const int* __restrict__ cp, int* __restrict__ ind) {
    int s = blockIdx.x * blockDim.x + threadIdx.x;
    if (s >= SSZ) return;
    int a = 0;
#pragma unroll
    for (int b = 0; b < BSZ; ++b) a |= cp[b * SSZ + s];
    ind[s] = (s == 0) ? 0 : (a != 0 ? 1 : 0);
}

// --- Kernel 2: scan -> chunk metadata + sorted norm items; zero counters -
__global__ __launch_bounds__(1024) void scan_kernel(const int* __restrict__ ind,
                                                    int* __restrict__ ch_s0,
                                                    int* __restrict__ ch_s1,
                                                    int* __restrict__ ch_c0,
                                                    int* __restrict__ ch_n,
                                                    int* __restrict__ ch_seg,
                                                    float* __restrict__ ch_rc,
                                                    int* __restrict__ srt_st,
                                                    int* __restrict__ srt_en,
                                                    int* __restrict__ srt_seg,
                                                    int* __restrict__ ctr,
                                                    int* __restrict__ meta) {
    __shared__ int ldsi[1024];
    __shared__ int sstart[SEGCAP];
    __shared__ int snseg;
    const int t = threadIdx.x;
    for (int i = t; i < CHCAP * BSZ; i += 1024) ctr[i] = 0;  // replay-safe

    int vals[8];
    int tot = 0;
#pragma unroll
    for (int i = 0; i < 8; ++i) { int v = ind[t * 8 + i]; vals[i] = v; tot += v; }
    ldsi[t] = tot;
    __syncthreads();
    for (int off = 1; off < 1024; off <<= 1) {
        int a = ldsi[t];
        int b = (t >= off) ? ldsi[t - off] : 0;
        __syncthreads();
        ldsi[t] = a + b;
        __syncthreads();
    }
    int run = ldsi[t] - tot;
#pragma unroll
    for (int i = 0; i < 8; ++i) {
        run += vals[i];
        if (vals[i] && run < SEGCAP) sstart[run] = t * 8 + i;
    }
    if (t == 0) sstart[0] = 0;
    if (t == 1023) { int n = ldsi[1023] + 1; snseg = n < SEGCAP ? n : SEGCAP; }
    __syncthreads();

    const int nseg = snseg;
    int st = 0, en = 0, nch = 0;
    if (t < nseg) {
        st = sstart[t];
        en = (t + 1 < nseg) ? sstart[t + 1] : SSZ;
        nch = (en - st + CH - 1) / CH;
    }
    ldsi[t] = nch;
    __syncthreads();
    for (int off = 1; off < 1024; off <<= 1) {
        int a = ldsi[t];
        int b = (t >= off) ? ldsi[t - off] : 0;
        __syncthreads();
        ldsi[t] = a + b;
        __syncthreads();
    }
    const int cbase = ldsi[t] - nch;
    if (t < nseg) {
        const float rc = 1.0f / (float)(en - st);
        for (int j = 0; j < nch; ++j) {
            const int c = cbase + j;
            ch_s0[c] = st + j * CH;
            ch_s1[c] = min(en, st + (j + 1) * CH);
            ch_c0[c] = cbase;
            ch_n[c]  = nch;
            ch_seg[c] = t;
            ch_rc[c] = rc;
        }
        // stable length-descending rank for the norm pass
        const int len = en - st;
        int rank = 0;
        for (int j = 0; j < nseg; ++j) {
            const int lj = ((j + 1 < nseg) ? sstart[j + 1] : SSZ) - sstart[j];
            rank += (lj > len) || (lj == len && j < t);
        }
        srt_st[rank] = st;
        srt_en[rank] = en;
        srt_seg[rank] = t;
    }
    if (t == 1023) {
        meta[0] = ldsi[1023] * BSZ;   // stats items = nchunks * BSZ
        meta[1] = nseg * BSZ * 2;     // norm items
    }
}

// --- Kernel 3: balanced stats + in-kernel closer finalize ----------------
__global__ __launch_bounds__(256) void stats_kernel(const f32x4* __restrict__ x4,
                                                    const int* __restrict__ ch_s0,
                                                    const int* __restrict__ ch_s1,
                                                    const int* __restrict__ ch_c0,
                                                    const int* __restrict__ ch_n,
                                                    const int* __restrict__ ch_seg,
                                                    const float* __restrict__ ch_rc,
                                                    const int* __restrict__ meta,
                                                    f32x4* __restrict__ psum,
                                                    f32x4* __restrict__ pssq,
                                                    int* __restrict__ ctr,
                                                    f32x4* __restrict__ mean4,
                                                    f32x4* __restrict__ rstd4) {
    __shared__ f32x4 lsum[4][64];
    __shared__ f32x4 lssq[4][64];
    __shared__ int lcloser;
    const int nitems = meta[0];
    const int lane = threadIdx.x & 63;
    const int wave = threadIdx.x >> 6;
    for (int item = blockIdx.x; item < nitems; item += NBLK_S) {
        const int c = item >> 4;
        const int b = item & 15;
        const int s0 = ch_s0[c], s1 = ch_s1[c];
        const int n = ch_n[c];
        const f32x4* px = x4 + (size_t)b * SSZ * F4 + lane;

        f32x4 sum = {0.f, 0.f, 0.f, 0.f};
        f32x4 ssq = {0.f, 0.f, 0.f, 0.f};
        for (int s = s0 + wave; s < s1; s += 4) {
            f32x4 v = px[(size_t)s * F4];
            sum += v;
            ssq += v * v;
        }
        lsum[wave][lane] = sum;
        lssq[wave][lane] = ssq;
        __syncthreads();

        if (n == 1) {
            // whole segment in this item: write final mean/rstd directly
            if (wave == 0) {
                f32x4 S = lsum[0][lane] + lsum[1][lane] + lsum[2][lane] + lsum[3][lane];
                f32x4 Q = lssq[0][lane] + lssq[1][lane] + lssq[2][lane] + lssq[3][lane];
                const float rc = ch_rc[c];
                const int seg = ch_seg[c];
                f32x4 m = S * rc;
                f32x4 var = Q * rc - m * m;
                f32x4 r;
                r.x = 1.0f / sqrtf(fmaxf(var.x, 0.f) + EPSV);
                r.y = 1.0f / sqrtf(fmaxf(var.y, 0.f) + EPSV);
                r.z = 1.0f / sqrtf(fmaxf(var.z, 0.f) + EPSV);
                r.w = 1.0f / sqrtf(fmaxf(var.w, 0.f) + EPSV);
                mean4[((size_t)seg * BSZ + b) * F4 + lane] = m;
                rstd4[((size_t)seg * BSZ + b) * F4 + lane] = r;
            }
            __syncthreads();
        } else {
            // publish this chunk's partial, last arriver finalizes the group
            if (wave == 0) {
                f32x4 o = lsum[0][lane] + lsum[1][lane] + lsum[2][lane] + lsum[3][lane];
                psum[((size_t)c * BSZ + b) * F4 + lane] = o;
            } else if (wave == 1) {
                f32x4 o = lssq[0][lane] + lssq[1][lane] + lssq[2][lane] + lssq[3][lane];
                pssq[((size_t)c * BSZ + b) * F4 + lane] = o;
            }
            __threadfence();   // partials visible device-wide before count
            __syncthreads();
            const int c0 = ch_c0[c];
            if (threadIdx.x == 0) {
                int ret = __hip_atomic_fetch_add(&ctr[c0 * BSZ + b], 1,
                                                 __ATOMIC_ACQ_REL,
                                                 __HIP_MEMORY_SCOPE_AGENT);
                lcloser = (ret == n - 1);
            }
            __syncthreads();
            if (lcloser) {
                if (wave == 0) {
                    __builtin_amdgcn_fence(__ATOMIC_ACQUIRE, "agent");
                    f32x4 S = {0.f, 0.f, 0.f, 0.f};
                    f32x4 Q = {0.f, 0.f, 0.f, 0.f};
                    for (int cc = c0; cc < c0 + n; ++cc) {
                        S += psum[((size_t)cc * BSZ + b) * F4 + lane];
                        Q += pssq[((size_t)cc * BSZ + b) * F4 + lane];
                    }
                    const float rc = ch_rc[c];
                    const int seg = ch_seg[c];
                    f32x4 m = S * rc;
                    f32x4 var = Q * rc - m * m;
                    f32x4 r;
                    r.x = 1.0f / sqrtf(fmaxf(var.x, 0.f) + EPSV);
                    r.y = 1.0f / sqrtf(fmaxf(var.y, 0.f) + EPSV);
                    r.z = 1.0f / sqrtf(fmaxf(var.z, 0.f) + EPSV);
                    r.w = 1.0f / sqrtf(fmaxf(var.w, 0.f) + EPSV);
                    mean4[((size_t)seg * BSZ + b) * F4 + lane] = m;
                    rstd4[((size_t)seg * BSZ + b) * F4 + lane] = r;
                }
            }
            __syncthreads();
        }
    }
}

// --- Kernel 4: normalize. Item = (sorted rank, b, f-half), no barriers ---
__global__ __launch_bounds__(256) void norm_kernel(const f32x4* __restrict__ x4,
                                                   const f32x4* __restrict__ w4p,
                                                   const f32x4* __restrict__ b4p,
                                                   const int* __restrict__ srt_st,
                                                   const int* __restrict__ srt_en,
                                                   const int* __restrict__ srt_seg,
                                                   const int* __restrict__ meta,
                                                   const f32x4* __restrict__ mean4,
                                                   const f32x4* __restrict__ rstd4,
                                                   f32x4* __restrict__ out4) {
    const int nitems = meta[1];        // nseg * BSZ * 2
    const int col = threadIdx.x & 31;
    const int rg = threadIdx.x >> 5;

    for (int item = blockIdx.x; item < nitems; item += NBLK_N) {
        const int k = item >> 5;       // longest-first rank
        const int b = (item >> 1) & 15;
        const int fh = item & 1;
        const int st = srt_st[k];
        const int en = srt_en[k];
        const int seg = srt_seg[k];
        const int fc = fh * 32 + col;

        const f32x4 m = mean4[((size_t)seg * BSZ + b) * F4 + fc];
        const f32x4 r = rstd4[((size_t)seg * BSZ + b) * F4 + fc];
        const f32x4 w = w4p[fc];
        const f32x4 bb = b4p[fc];

        const f32x4* px = x4 + (size_t)b * SSZ * F4 + fc;
        f32x4* po = out4 + (size_t)b * SSZ * F4 + fc;
        for (int s = st + rg; s < en; s += 8) {
            f32x4 v = px[(size_t)s * F4];
            f32x4 o = (v - m) * r * w + bb;
            __builtin_nontemporal_store(o, &po[(size_t)s * F4]);
        }
    }
}

extern "C" void kernel_launch(void* const* d_in, const int* in_sizes, int n_in,
                              void* d_out, int out_size, void* d_ws, size_t ws_size,
                              hipStream_t stream) {
    const f32x4* x = (const f32x4*)d_in[0];
    const f32x4* w = (const f32x4*)d_in[1];
    const f32x4* bias = (const f32x4*)d_in[2];
    const int* cp = (const int*)d_in[3];

    char* ws = (char*)d_ws;
    int*   meta  = (int*)ws;                 // [16]
    int*   ch_s0 = (int*)(ws + 2048);        // [CHCAP]
    int*   ch_s1 = (int*)(ws + 4096);        // [CHCAP]
    int*   ch_c0 = (int*)(ws + 6144);        // [CHCAP]
    int*   ch_n  = (int*)(ws + 8192);        // [CHCAP]
    int*   ch_seg= (int*)(ws + 10240);       // [CHCAP]
    float* ch_rc = (float*)(ws + 12288);     // [CHCAP]
    int*   srt_st = (int*)(ws + 14336);      // [SEGCAP]
    int*   srt_en = (int*)(ws + 16384);      // [SEGCAP]
    int*   srt_seg= (int*)(ws + 18432);      // [SEGCAP]
    int*   ctr   = (int*)(ws + 32768);       // [CHCAP*BSZ] = 24 KB
    int*   ind   = (int*)(ws + 65536);       // [SSZ]
    f32x4* psum  = (f32x4*)(ws + 131072);    // CHCAP*BSZ*F4 = 6.29 MB
    f32x4* pssq  = psum + (size_t)CHCAP * BSZ * F4;
    f32x4* mean4 = pssq + (size_t)CHCAP * BSZ * F4;   // SEGCAP*BSZ*F4 = 4.2 MB
    f32x4* rstd4 = mean4 + (size_t)SEGCAP * BSZ * F4;

    cp_reduce_kernel<<<32, 256, 0, stream>>>(cp, ind);
    scan_kernel<<<1, 1024, 0, stream>>>(ind, ch_s0, ch_s1, ch_c0, ch_n, ch_seg,
                                        ch_rc, srt_st, srt_en, srt_seg, ctr, meta);
    stats_kernel<<<NBLK_S, 256, 0, stream>>>(x, ch_s0, ch_s1, ch_c0, ch_n, ch_seg,
                                             ch_rc, meta, psum, pssq, ctr,
                                             mean4, rstd4);
    norm_kernel<<<NBLK_N, 256, 0, stream>>>(x, w, bias, srt_st, srt_en, srt_seg,
                                            meta, mean4, rstd4, (f32x4*)d_out);
}

// Round 10
// 93.483 us; speedup vs baseline: 4.5903x; 3.5468x over previous
//
#include <hip/hip_runtime.h>

#define BSZ 16
#define SSZ 8192
#define F4  64
#define EPSV 1e-5f
#define SEGCAP 256     // nseg ~131 expected (sigma ~11) -> huge margin
#define CHCAP  384     // max chunks = SSZ/CH (128) + SEGCAP
#define CH 64
#define NBLK_S 4096
#define NBLK_N 2048

typedef float f32x4 __attribute__((ext_vector_type(4)));

// --- Kernel 1: ind[s] = any_b(cp[b,s]), ind[0]=0 -------------------------
__global__ void cp_reduce_kernel(const int* __restrict__ cp, int* __restrict__ ind) {
    int s = blockIdx.x * blockDim.x + threadIdx.x;
    if (s >= SSZ) return;
    int a = 0;
#pragma unroll
    for (int b = 0; b < BSZ; ++b) a |= cp[b * SSZ + s];
    ind[s] = (s == 0) ? 0 : (a != 0 ? 1 : 0);
}

// --- Kernel 2: scan -> chunk metadata + seg_id; zero closer counters -----
__global__ __launch_bounds__(1024) void scan_kernel(const int* __restrict__ ind,
                                                    int* __restrict__ ch_s0,
                                                    int* __restrict__ ch_s1,
                                                    int* __restrict__ ch_c0,
                                                    int* __restrict__ ch_n,
                                                    int* __restrict__ ch_seg,
                                                    float* __restrict__ ch_rc,
                                                    int* __restrict__ seg_id,
                                                    int* __restrict__ ctr,
                                                    int* __restrict__ meta) {
    __shared__ int ldsi[1024];
    __shared__ int sstart[SEGCAP];
    __shared__ int snseg;
    const int t = threadIdx.x;
    for (int i = t; i < CHCAP * BSZ; i += 1024) ctr[i] = 0;  // replay-safe

    int vals[8];
    int tot = 0;
#pragma unroll
    for (int i = 0; i < 8; ++i) { int v = ind[t * 8 + i]; vals[i] = v; tot += v; }
    ldsi[t] = tot;
    __syncthreads();
    for (int off = 1; off < 1024; off <<= 1) {
        int a = ldsi[t];
        int b = (t >= off) ? ldsi[t - off] : 0;
        __syncthreads();
        ldsi[t] = a + b;
        __syncthreads();
    }
    int run = ldsi[t] - tot;  // exclusive prefix
#pragma unroll
    for (int i = 0; i < 8; ++i) {
        run += vals[i];
        int r = run < SEGCAP ? run : SEGCAP - 1;
        if (vals[i] && run < SEGCAP) sstart[run] = t * 8 + i;
        seg_id[t * 8 + i] = r;
    }
    if (t == 0) sstart[0] = 0;
    if (t == 1023) { int n = ldsi[1023] + 1; snseg = n < SEGCAP ? n : SEGCAP; }
    __syncthreads();

    const int nseg = snseg;
    int st = 0, en = 0, nch = 0;
    if (t < nseg) {
        st = sstart[t];
        en = (t + 1 < nseg) ? sstart[t + 1] : SSZ;
        nch = (en - st + CH - 1) / CH;
    }
    ldsi[t] = nch;
    __syncthreads();
    for (int off = 1; off < 1024; off <<= 1) {
        int a = ldsi[t];
        int b = (t >= off) ? ldsi[t - off] : 0;
        __syncthreads();
        ldsi[t] = a + b;
        __syncthreads();
    }
    const int cbase = ldsi[t] - nch;  // exclusive prefix
    if (t < nseg) {
        const float rc = 1.0f / (float)(en - st);
        for (int j = 0; j < nch; ++j) {
            const int c = cbase + j;
            ch_s0[c] = st + j * CH;
            ch_s1[c] = min(en, st + (j + 1) * CH);
            ch_c0[c] = cbase;
            ch_n[c]  = nch;
            ch_seg[c] = t;
            ch_rc[c] = rc;
        }
    }
    if (t == 1023) meta[0] = ldsi[1023] * BSZ;   // stats items
}

// --- Kernel 3: balanced stats + FENCE-FREE closer finalize ---------------
// Protocol: partials published via agent-scope relaxed atomic stores
// (write-through, globally visible once vmcnt retires); __syncthreads()
// drains vmcnt; then a relaxed agent fetch_add elects the closer, which
// re-reads partials via agent-scope relaxed atomic loads (cache-bypassing).
// No fences -> no L2 writeback-invalidate storms (the R8/R9 killer).
__global__ __launch_bounds__(256) void stats_kernel(const f32x4* __restrict__ x4,
                                                    const int* __restrict__ ch_s0,
                                                    const int* __restrict__ ch_s1,
                                                    const int* __restrict__ ch_c0,
                                                    const int* __restrict__ ch_n,
                                                    const int* __restrict__ ch_seg,
                                                    const float* __restrict__ ch_rc,
                                                    const int* __restrict__ meta,
                                                    float* __restrict__ psum,
                                                    float* __restrict__ pssq,
                                                    int* __restrict__ ctr,
                                                    f32x4* __restrict__ mean4,
                                                    f32x4* __restrict__ rstd4) {
    __shared__ f32x4 lsum[4][64];
    __shared__ f32x4 lssq[4][64];
    __shared__ int lcloser;
    const int nitems = meta[0];
    const int lane = threadIdx.x & 63;
    const int wave = threadIdx.x >> 6;
    for (int item = blockIdx.x; item < nitems; item += NBLK_S) {
        const int c = item >> 4;
        const int b = item & 15;
        const int s0 = ch_s0[c], s1 = ch_s1[c];
        const int n = ch_n[c];
        const int seg = ch_seg[c];
        const float rc = ch_rc[c];
        const f32x4* px = x4 + (size_t)b * SSZ * F4 + lane;

        f32x4 sum = {0.f, 0.f, 0.f, 0.f};
        f32x4 ssq = {0.f, 0.f, 0.f, 0.f};
        for (int s = s0 + wave; s < s1; s += 4) {
            f32x4 v = px[(size_t)s * F4];
            sum += v;
            ssq += v * v;
        }
        lsum[wave][lane] = sum;
        lssq[wave][lane] = ssq;
        __syncthreads();

        if (n == 1) {
            // whole segment in this item: finalize locally, plain stores
            // (norm kernel visibility via kernel boundary)
            if (wave == 0) {
                f32x4 S = lsum[0][lane] + lsum[1][lane] + lsum[2][lane] + lsum[3][lane];
                f32x4 Q = lssq[0][lane] + lssq[1][lane] + lssq[2][lane] + lssq[3][lane];
                f32x4 m = S * rc;
                f32x4 var = Q * rc - m * m;
                f32x4 r;
                r.x = 1.0f / sqrtf(fmaxf(var.x, 0.f) + EPSV);
                r.y = 1.0f / sqrtf(fmaxf(var.y, 0.f) + EPSV);
                r.z = 1.0f / sqrtf(fmaxf(var.z, 0.f) + EPSV);
                r.w = 1.0f / sqrtf(fmaxf(var.w, 0.f) + EPSV);
                mean4[((size_t)seg * BSZ + b) * F4 + lane] = m;
                rstd4[((size_t)seg * BSZ + b) * F4 + lane] = r;
            }
            __syncthreads();
        } else {
            const int c0 = ch_c0[c];
            // publish partial: agent-scope relaxed atomic stores (no fence)
            const size_t pb = ((size_t)c * BSZ + b) * F4 * 4 + lane * 4;
            if (wave == 0) {
                f32x4 o = lsum[0][lane] + lsum[1][lane] + lsum[2][lane] + lsum[3][lane];
#pragma unroll
                for (int j = 0; j < 4; ++j)
                    __hip_atomic_store(&psum[pb + j], o[j], __ATOMIC_RELAXED,
                                       __HIP_MEMORY_SCOPE_AGENT);
            } else if (wave == 1) {
                f32x4 o = lssq[0][lane] + lssq[1][lane] + lssq[2][lane] + lssq[3][lane];
#pragma unroll
                for (int j = 0; j < 4; ++j)
                    __hip_atomic_store(&pssq[pb + j], o[j], __ATOMIC_RELAXED,
                                       __HIP_MEMORY_SCOPE_AGENT);
            }
            __syncthreads();   // s_waitcnt vmcnt(0) before s_barrier: stores done
            if (threadIdx.x == 0) {
                int ret = __hip_atomic_fetch_add(&ctr[c0 * BSZ + b], 1,
                                                 __ATOMIC_RELAXED,
                                                 __HIP_MEMORY_SCOPE_AGENT);
                lcloser = (ret == n - 1);
            }
            __syncthreads();
            if (lcloser && wave == 0) {
                f32x4 S = {0.f, 0.f, 0.f, 0.f};
                f32x4 Q = {0.f, 0.f, 0.f, 0.f};
                for (int cc = c0; cc < c0 + n; ++cc) {
                    const size_t qb = ((size_t)cc * BSZ + b) * F4 * 4 + lane * 4;
#pragma unroll
                    for (int j = 0; j < 4; ++j) {
                        S[j] += __hip_atomic_load(&psum[qb + j], __ATOMIC_RELAXED,
                                                  __HIP_MEMORY_SCOPE_AGENT);
                        Q[j] += __hip_atomic_load(&pssq[qb + j], __ATOMIC_RELAXED,
                                                  __HIP_MEMORY_SCOPE_AGENT);
                    }
                }
                f32x4 m = S * rc;
                f32x4 var = Q * rc - m * m;
                f32x4 r;
                r.x = 1.0f / sqrtf(fmaxf(var.x, 0.f) + EPSV);
                r.y = 1.0f / sqrtf(fmaxf(var.y, 0.f) + EPSV);
                r.z = 1.0f / sqrtf(fmaxf(var.z, 0.f) + EPSV);
                r.w = 1.0f / sqrtf(fmaxf(var.w, 0.f) + EPSV);
                mean4[((size_t)seg * BSZ + b) * F4 + lane] = m;
                rstd4[((size_t)seg * BSZ + b) * F4 + lane] = r;
            }
            __syncthreads();
        }
    }
}

// --- Kernel 4: uniform normalize pass (R5's exact best-measured shape) ---
__global__ __launch_bounds__(256) void norm_kernel(const f32x4* __restrict__ x4,
                                                   const f32x4* __restrict__ w4p,
                                                   const f32x4* __restrict__ b4p,
                                                   const int* __restrict__ seg_id,
                                                   const f32x4* __restrict__ mean4,
                                                   const f32x4* __restrict__ rstd4,
                                                   f32x4* __restrict__ out4) {
    int tid = blockIdx.x * blockDim.x + threadIdx.x;  // 524288 = 8192 s * 64 f4
    int f4i = tid & 63;
    int s = tid >> 6;
    f32x4 w = w4p[f4i];
    f32x4 bb = b4p[f4i];
    int seg = seg_id[s];
    size_t xi = (size_t)s * F4 + f4i;
    int mi = (seg * BSZ) * F4 + f4i;
#pragma unroll
    for (int b = 0; b < BSZ; ++b) {
        f32x4 v = x4[xi + (size_t)b * SSZ * F4];
        f32x4 m = mean4[mi + b * F4];
        f32x4 r = rstd4[mi + b * F4];
        f32x4 o = (v - m) * r * w + bb;
        __builtin_nontemporal_store(o, &out4[xi + (size_t)b * SSZ * F4]);
    }
}

extern "C" void kernel_launch(void* const* d_in, const int* in_sizes, int n_in,
                              void* d_out, int out_size, void* d_ws, size_t ws_size,
                              hipStream_t stream) {
    const f32x4* x = (const f32x4*)d_in[0];
    const f32x4* w = (const f32x4*)d_in[1];
    const f32x4* bias = (const f32x4*)d_in[2];
    const int* cp = (const int*)d_in[3];

    char* ws = (char*)d_ws;
    int*   meta  = (int*)ws;                 // [16]
    int*   ch_s0 = (int*)(ws + 2048);        // [CHCAP]
    int*   ch_s1 = (int*)(ws + 4096);        // [CHCAP]
    int*   ch_c0 = (int*)(ws + 6144);        // [CHCAP]
    int*   ch_n  = (int*)(ws + 8192);        // [CHCAP]
    int*   ch_seg= (int*)(ws + 10240);       // [CHCAP]
    float* ch_rc = (float*)(ws + 12288);     // [CHCAP]
    int*   ctr   = (int*)(ws + 32768);       // [CHCAP*BSZ] = 24 KB
    int*   seg_id= (int*)(ws + 65536);       // [SSZ]
    int*   ind   = (int*)(ws + 98304);       // [SSZ]
    float* psum  = (float*)(ws + 131072);    // CHCAP*BSZ*FSZ = 6.29 MB
    float* pssq  = psum + (size_t)CHCAP * BSZ * F4 * 4;
    f32x4* mean4 = (f32x4*)(pssq + (size_t)CHCAP * BSZ * F4 * 4);  // 4.2 MB
    f32x4* rstd4 = mean4 + (size_t)SEGCAP * BSZ * F4;

    cp_reduce_kernel<<<32, 256, 0, stream>>>(cp, ind);
    scan_kernel<<<1, 1024, 0, stream>>>(ind, ch_s0, ch_s1, ch_c0, ch_n, ch_seg,
                                        ch_rc, seg_id, ctr, meta);
    stats_kernel<<<NBLK_S, 256, 0, stream>>>(x, ch_s0, ch_s1, ch_c0, ch_n, ch_seg,
                                             ch_rc, meta, psum, pssq, ctr,
                                             mean4, rstd4);
    norm_kernel<<<NBLK_N, 256, 0, stream>>>(x, w, bias, seg_id, mean4, rstd4,
                                            (f32x4*)d_out);
}

// Round 11
// 92.586 us; speedup vs baseline: 4.6348x; 1.0097x over previous
//
#include <hip/hip_runtime.h>

#define BSZ 16
#define SSZ 8192
#define F4  64
#define EPSV 1e-5f
#define SEGCAP 256     // nseg ~131 expected (sigma ~11) -> huge margin
#define CHCAP  384     // max chunks = SSZ/CH (128) + SEGCAP
#define CH 64
#define NBLK_S 4096

typedef float f32x4 __attribute__((ext_vector_type(4)));

__device__ __forceinline__ int wave_scan_incl(int x) {
    const int lane = threadIdx.x & 63;
#pragma unroll
    for (int o = 1; o < 64; o <<= 1) {
        int v = __shfl_up(x, o, 64);
        if (lane >= o) x += v;
    }
    return x;
}

// inclusive scan over 1024 threads; 2 barriers; lds16 = __shared__ int[16]
__device__ __forceinline__ int block_scan_incl(int x, int* lds16) {
    const int wid = threadIdx.x >> 6;
    const int lane = threadIdx.x & 63;
    int w = wave_scan_incl(x);
    if (lane == 63) lds16[wid] = w;
    __syncthreads();
    int base = 0;
#pragma unroll
    for (int j = 0; j < 16; ++j) base += (j < wid) ? lds16[j] : 0;
    __syncthreads();   // lds16 reusable after this
    return base + w;
}

// --- Kernel 1: fused cp-reduce + scan -> chunk metadata + seg_id ---------
__global__ __launch_bounds__(1024) void scan_kernel(const int* __restrict__ cp,
                                                    int* __restrict__ ch_s0,
                                                    int* __restrict__ ch_s1,
                                                    int* __restrict__ ch_c0,
                                                    int* __restrict__ ch_n,
                                                    int* __restrict__ ch_seg,
                                                    float* __restrict__ ch_rc,
                                                    int* __restrict__ seg_id,
                                                    int* __restrict__ ctr,
                                                    int* __restrict__ meta) {
    __shared__ int lds16[16];
    __shared__ int sstart[SEGCAP];
    __shared__ int snseg;
    __shared__ int stot;
    const int t = threadIdx.x;
    for (int i = t; i < CHCAP * BSZ; i += 1024) ctr[i] = 0;  // replay-safe

    // fused cp_reduce: this thread owns s = t*8 .. t*8+7
    int vals[8];
    {
        const int4* cp4 = (const int4*)cp;
        int4 a0 = {0, 0, 0, 0}, a1 = {0, 0, 0, 0};
#pragma unroll
        for (int b = 0; b < BSZ; ++b) {
            int4 u = cp4[b * 2048 + t * 2];
            int4 v = cp4[b * 2048 + t * 2 + 1];
            a0.x |= u.x; a0.y |= u.y; a0.z |= u.z; a0.w |= u.w;
            a1.x |= v.x; a1.y |= v.y; a1.z |= v.z; a1.w |= v.w;
        }
        vals[0] = a0.x != 0; vals[1] = a0.y != 0; vals[2] = a0.z != 0; vals[3] = a0.w != 0;
        vals[4] = a1.x != 0; vals[5] = a1.y != 0; vals[6] = a1.z != 0; vals[7] = a1.w != 0;
        if (t == 0) vals[0] = 0;   // position 0 never splits
    }
    int tot = 0;
#pragma unroll
    for (int i = 0; i < 8; ++i) tot += vals[i];

    const int incl = block_scan_incl(tot, lds16);
    int run = incl - tot;  // exclusive prefix
#pragma unroll
    for (int i = 0; i < 8; ++i) {
        run += vals[i];
        int r = run < SEGCAP ? run : SEGCAP - 1;
        if (vals[i] && run < SEGCAP) sstart[run] = t * 8 + i;
        seg_id[t * 8 + i] = r;
    }
    if (t == 0) sstart[0] = 0;
    if (t == 1023) { int n = incl + 1; snseg = n < SEGCAP ? n : SEGCAP; }
    __syncthreads();

    const int nseg = snseg;
    int st = 0, en = 0, nch = 0;
    if (t < nseg) {
        st = sstart[t];
        en = (t + 1 < nseg) ? sstart[t + 1] : SSZ;
        nch = (en - st + CH - 1) / CH;
    }
    const int incl2 = block_scan_incl(nch, lds16);
    const int cbase = incl2 - nch;
    if (t < nseg) {
        const float rc = 1.0f / (float)(en - st);
        for (int j = 0; j < nch; ++j) {
            const int c = cbase + j;
            ch_s0[c] = st + j * CH;
            ch_s1[c] = min(en, st + (j + 1) * CH);
            ch_c0[c] = cbase;
            ch_n[c]  = nch;
            ch_seg[c] = t;
            ch_rc[c] = rc;
        }
    }
    if (t == 1023) stot = incl2;   // total chunks
    __syncthreads();
    if (t == 0) meta[0] = stot * BSZ;
}

// --- Kernel 2: balanced stats + FENCE-FREE closer finalize (R10 proven) --
__global__ __launch_bounds__(256) void stats_kernel(const f32x4* __restrict__ x4,
                                                    const int* __restrict__ ch_s0,
                                                    const int* __restrict__ ch_s1,
                                                    const int* __restrict__ ch_c0,
                                                    const int* __restrict__ ch_n,
                                                    const int* __restrict__ ch_seg,
                                                    const float* __restrict__ ch_rc,
                                                    const int* __restrict__ meta,
                                                    float* __restrict__ psum,
                                                    float* __restrict__ pssq,
                                                    int* __restrict__ ctr,
                                                    f32x4* __restrict__ mean4,
                                                    f32x4* __restrict__ rstd4) {
    __shared__ f32x4 lsum[4][64];
    __shared__ f32x4 lssq[4][64];
    __shared__ int lcloser;
    const int nitems = meta[0];
    const int lane = threadIdx.x & 63;
    const int wave = threadIdx.x >> 6;
    for (int item = blockIdx.x; item < nitems; item += NBLK_S) {
        const int c = item >> 4;
        const int b = item & 15;
        const int s0 = ch_s0[c], s1 = ch_s1[c];
        const int n = ch_n[c];
        const int seg = ch_seg[c];
        const float rc = ch_rc[c];
        const f32x4* px = x4 + (size_t)b * SSZ * F4 + lane;

        f32x4 sum = {0.f, 0.f, 0.f, 0.f};
        f32x4 ssq = {0.f, 0.f, 0.f, 0.f};
        for (int s = s0 + wave; s < s1; s += 4) {
            f32x4 v = px[(size_t)s * F4];
            sum += v;
            ssq += v * v;
        }
        lsum[wave][lane] = sum;
        lssq[wave][lane] = ssq;
        __syncthreads();

        if (n == 1) {
            if (wave == 0) {
                f32x4 S = lsum[0][lane] + lsum[1][lane] + lsum[2][lane] + lsum[3][lane];
                f32x4 Q = lssq[0][lane] + lssq[1][lane] + lssq[2][lane] + lssq[3][lane];
                f32x4 m = S * rc;
                f32x4 var = Q * rc - m * m;
                f32x4 r;
                r.x = 1.0f / sqrtf(fmaxf(var.x, 0.f) + EPSV);
                r.y = 1.0f / sqrtf(fmaxf(var.y, 0.f) + EPSV);
                r.z = 1.0f / sqrtf(fmaxf(var.z, 0.f) + EPSV);
                r.w = 1.0f / sqrtf(fmaxf(var.w, 0.f) + EPSV);
                mean4[((size_t)seg * BSZ + b) * F4 + lane] = m;
                rstd4[((size_t)seg * BSZ + b) * F4 + lane] = r;
            }
            __syncthreads();
        } else {
            const int c0 = ch_c0[c];
            const size_t pb = ((size_t)c * BSZ + b) * F4 * 4 + lane * 4;
            if (wave == 0) {
                f32x4 o = lsum[0][lane] + lsum[1][lane] + lsum[2][lane] + lsum[3][lane];
#pragma unroll
                for (int j = 0; j < 4; ++j)
                    __hip_atomic_store(&psum[pb + j], o[j], __ATOMIC_RELAXED,
                                       __HIP_MEMORY_SCOPE_AGENT);
            } else if (wave == 1) {
                f32x4 o = lssq[0][lane] + lssq[1][lane] + lssq[2][lane] + lssq[3][lane];
#pragma unroll
                for (int j = 0; j < 4; ++j)
                    __hip_atomic_store(&pssq[pb + j], o[j], __ATOMIC_RELAXED,
                                       __HIP_MEMORY_SCOPE_AGENT);
            }
            __syncthreads();   // vmcnt drained before barrier: stores visible
            if (threadIdx.x == 0) {
                int ret = __hip_atomic_fetch_add(&ctr[c0 * BSZ + b], 1,
                                                 __ATOMIC_RELAXED,
                                                 __HIP_MEMORY_SCOPE_AGENT);
                lcloser = (ret == n - 1);
            }
            __syncthreads();
            if (lcloser && wave == 0) {
                f32x4 S = {0.f, 0.f, 0.f, 0.f};
                f32x4 Q = {0.f, 0.f, 0.f, 0.f};
                for (int cc = c0; cc < c0 + n; ++cc) {
                    const size_t qb = ((size_t)cc * BSZ + b) * F4 * 4 + lane * 4;
#pragma unroll
                    for (int j = 0; j < 4; ++j) {
                        S[j] += __hip_atomic_load(&psum[qb + j], __ATOMIC_RELAXED,
                                                  __HIP_MEMORY_SCOPE_AGENT);
                        Q[j] += __hip_atomic_load(&pssq[qb + j], __ATOMIC_RELAXED,
                                                  __HIP_MEMORY_SCOPE_AGENT);
                    }
                }
                f32x4 m = S * rc;
                f32x4 var = Q * rc - m * m;
                f32x4 r;
                r.x = 1.0f / sqrtf(fmaxf(var.x, 0.f) + EPSV);
                r.y = 1.0f / sqrtf(fmaxf(var.y, 0.f) + EPSV);
                r.z = 1.0f / sqrtf(fmaxf(var.z, 0.f) + EPSV);
                r.w = 1.0f / sqrtf(fmaxf(var.w, 0.f) + EPSV);
                mean4[((size_t)seg * BSZ + b) * F4 + lane] = m;
                rstd4[((size_t)seg * BSZ + b) * F4 + lane] = r;
            }
            __syncthreads();
        }
    }
}

// --- Kernel 3: flat normalize, one f32x4 element per thread --------------
__global__ __launch_bounds__(256) void norm_kernel(const f32x4* __restrict__ x4,
                                                   const f32x4* __restrict__ w4p,
                                                   const f32x4* __restrict__ b4p,
                                                   const int* __restrict__ seg_id,
                                                   const f32x4* __restrict__ mean4,
                                                   const f32x4* __restrict__ rstd4,
                                                   f32x4* __restrict__ out4) {
    const int tid = blockIdx.x * 256 + threadIdx.x;  // [0, BSZ*SSZ*F4)
    const int f4i = tid & 63;
    const int s = (tid >> 6) & (SSZ - 1);
    const int b = tid >> 19;                         // / (SSZ*F4)
    const int seg = seg_id[s];
    const f32x4 m = mean4[((size_t)seg * BSZ + b) * F4 + f4i];
    const f32x4 r = rstd4[((size_t)seg * BSZ + b) * F4 + f4i];
    const f32x4 w = w4p[f4i];
    const f32x4 bb = b4p[f4i];
    const f32x4 v = x4[(size_t)tid];
    f32x4 o = (v - m) * r * w + bb;
    __builtin_nontemporal_store(o, &out4[(size_t)tid]);
}

extern "C" void kernel_launch(void* const* d_in, const int* in_sizes, int n_in,
                              void* d_out, int out_size, void* d_ws, size_t ws_size,
                              hipStream_t stream) {
    const f32x4* x = (const f32x4*)d_in[0];
    const f32x4* w = (const f32x4*)d_in[1];
    const f32x4* bias = (const f32x4*)d_in[2];
    const int* cp = (const int*)d_in[3];

    char* ws = (char*)d_ws;
    int*   meta  = (int*)ws;                 // [16]
    int*   ch_s0 = (int*)(ws + 2048);        // [CHCAP]
    int*   ch_s1 = (int*)(ws + 4096);        // [CHCAP]
    int*   ch_c0 = (int*)(ws + 6144);        // [CHCAP]
    int*   ch_n  = (int*)(ws + 8192);        // [CHCAP]
    int*   ch_seg= (int*)(ws + 10240);       // [CHCAP]
    float* ch_rc = (float*)(ws + 12288);     // [CHCAP]
    int*   ctr   = (int*)(ws + 32768);       // [CHCAP*BSZ] = 24 KB
    int*   seg_id= (int*)(ws + 65536);       // [SSZ]
    float* psum  = (float*)(ws + 131072);    // CHCAP*BSZ*FSZ = 6.29 MB
    float* pssq  = psum + (size_t)CHCAP * BSZ * F4 * 4;
    f32x4* mean4 = (f32x4*)(pssq + (size_t)CHCAP * BSZ * F4 * 4);  // 4.2 MB
    f32x4* rstd4 = mean4 + (size_t)SEGCAP * BSZ * F4;

    scan_kernel<<<1, 1024, 0, stream>>>(cp, ch_s0, ch_s1, ch_c0, ch_n, ch_seg,
                                        ch_rc, seg_id, ctr, meta);
    stats_kernel<<<NBLK_S, 256, 0, stream>>>(x, ch_s0, ch_s1, ch_c0, ch_n, ch_seg,
                                             ch_rc, meta, psum, pssq, ctr,
                                             mean4, rstd4);
    norm_kernel<<<BSZ * SSZ * F4 / 256, 256, 0, stream>>>(x, w, bias, seg_id,
                                                          mean4, rstd4,
                                                          (f32x4*)d_out);
}